// Round 3
// baseline (312.232 us; speedup 1.0000x reference)
//
#include <hip/hip_runtime.h>
#include <hip/hip_bf16.h>

// GemmRS: out[m,n] = sum_{w,k} A[w,m,k]*B[w,n,k]
// A: [8,8192,512] f32, B: [8,1024,512] f32, out: [8192,1024] f32.
//
// R1: dbuf LDS (1 barrier/K-step), bijective XCD swizzle, setprio.
// R2: 128x128 tile -> gemm ~63 us, AT the ds_read_b128 throughput ceiling
//     (~81 B/cyc/CU vs m134's 85): LDS-BW bound, 0 bank conflicts.
// R3: FUSE the f32->bf16 convert into the GEMM's reg-staging
//     (global f32 -> cvt in reg -> ds_write_b128). LDS bytes unchanged
//     (still bf16), so the gemm stays at its LDS wall, but the separate
//     227-MB cvt pass (~38 us) and the workspace round-trip disappear.
//     Numerics bit-identical (same RNE conversion, same MFMA order).
//     Pipeline (1 barrier/K-step):
//       ds_read frags(cur) -> [vmcnt; cvt; ds_write buf^1 (tile t+1)]
//       -> issue global loads (tile t+2) -> MFMA -> barrier.

#define WS 8
#define MM 8192
#define KK 512
#define NN 1024
#define KTOT (WS * KK)  // 4096
#define BM 128
#define BN 128
#define BK 64
#define NBLK ((MM / BM) * (NN / BN))  // 512, divisible by 8

typedef __attribute__((ext_vector_type(8))) short short8;
typedef __attribute__((ext_vector_type(4))) float floatx4;

static __device__ inline short f2bf(float f) {
    union { __hip_bfloat16 h; short s; } u;
    u.h = __float2bfloat16(f);  // RNE
    return u.s;
}

// 4 waves: wr in {0,1} (64 rows), wc in {0,1} (64 cols); 4x4 frags/wave,
// 32 MFMA/wave/K-step. LDS 64 KB (2 buf x (16+16) KB) -> 2 blocks/CU.
__global__ __launch_bounds__(256, 2)
void gemm_rs_fused2(const float* __restrict__ A, const float* __restrict__ B,
                    float* __restrict__ C) {
    __shared__ short As[2][BM * BK];  // 32 KB
    __shared__ short Bs[2][BN * BK];  // 32 KB

    const int tid  = threadIdx.x;
    const int lane = tid & 63;
    const int wid  = tid >> 6;

    // Bijective XCD swizzle: XCD j owns 64 consecutive tiles = 8 contiguous
    // M-panel rows (keeps per-XCD working set cache-local).
    const int lin = blockIdx.y * gridDim.x + blockIdx.x;       // 0..511
    const int T   = (lin & 7) * (NBLK / 8) + (lin >> 3);       // bijective
    const int ty  = T >> 3;          // 0..63  (M tile)
    const int tx  = T & 7;           // 0..7   (N tile)
    const int m0  = ty * BM;
    const int n0  = tx * BN;

    const int wr = wid >> 1, wc = wid & 1;
    const int lm = lane & 15, quad = lane >> 4;

    // Staging geometry: chunk = 64 lanes; lane -> (lrow = lane>>3, p = lane&7).
    // Stored position p of row r holds logical k-seg p ^ (r&7) (seg = 8 elems);
    // read side compensates with the same XOR. Source is f32 now: 8 f32 per
    // lane per chunk (two float4), converted to one short8 ds_write_b128.
    const int lrow = lane >> 3;
    const int p    = lane & 7;
    const int ss   = p ^ lrow;

    // f32 source element offsets within one rank-bank (w*stride + kk added per step)
    size_t gA[4], gB[4];
#pragma unroll
    for (int t = 0; t < 4; ++t) {
        gA[t] = (size_t)(m0 + wid * 32 + t * 8 + lrow) * KK + ss * 8;
        gB[t] = (size_t)(n0 + wid * 32 + t * 8 + lrow) * KK + ss * 8;
    }
    const int wbase = wid * 4 * 512 + lane * 8;  // LDS write base (shorts); +t*512

    floatx4 acc[4][4];
#pragma unroll
    for (int i = 0; i < 4; ++i)
#pragma unroll
        for (int j = 0; j < 4; ++j) acc[i][j] = (floatx4)0.f;

    float4 ra[4][2], rb[4][2];  // in-flight staging regs (64 VGPR)

    auto LOAD = [&](int kt) {
        const int w  = kt >> 9;         // rank bank (uniform)
        const int kk = kt & (KK - 1);   // offset inside bank (uniform)
        const float* Aw = A + (size_t)w * MM * KK + kk;
        const float* Bw = B + (size_t)w * NN * KK + kk;
#pragma unroll
        for (int t = 0; t < 4; ++t) {
            ra[t][0] = *(const float4*)(Aw + gA[t]);
            ra[t][1] = *(const float4*)(Aw + gA[t] + 4);
            rb[t][0] = *(const float4*)(Bw + gB[t]);
            rb[t][1] = *(const float4*)(Bw + gB[t] + 4);
        }
    };
    auto WRITE = [&](int buf) {
#pragma unroll
        for (int t = 0; t < 4; ++t) {
            short8 oa = { f2bf(ra[t][0].x), f2bf(ra[t][0].y),
                          f2bf(ra[t][0].z), f2bf(ra[t][0].w),
                          f2bf(ra[t][1].x), f2bf(ra[t][1].y),
                          f2bf(ra[t][1].z), f2bf(ra[t][1].w) };
            *(short8*)&As[buf][wbase + t * 512] = oa;
            short8 ob = { f2bf(rb[t][0].x), f2bf(rb[t][0].y),
                          f2bf(rb[t][0].z), f2bf(rb[t][0].w),
                          f2bf(rb[t][1].x), f2bf(rb[t][1].y),
                          f2bf(rb[t][1].z), f2bf(rb[t][1].w) };
            *(short8*)&Bs[buf][wbase + t * 512] = ob;
        }
    };

    // Prologue: tile 0 -> LDS buf0; tile 1 -> regs; one barrier.
    LOAD(0);
    WRITE(0);
    LOAD(BK);
    __syncthreads();

    for (int kt = 0; kt < KTOT; kt += BK) {
        const int cur = (kt >> 6) & 1;

        // Fragment reads first (critical path to MFMA).
        short8 af[2][4], bfr[2][4];
#pragma unroll
        for (int kc = 0; kc < 2; ++kc) {
#pragma unroll
            for (int i = 0; i < 4; ++i) {
                const int row = wr * 64 + i * 16 + lm;
                const int sa  = (kc * 4 + quad) ^ (lm & 7);
                af[kc][i] = *(const short8*)&As[cur][row * BK + sa * 8];
            }
#pragma unroll
            for (int j = 0; j < 4; ++j) {
                const int row = wc * 64 + j * 16 + lm;
                const int sb  = (kc * 4 + quad) ^ (lm & 7);
                bfr[kc][j] = *(const short8*)&Bs[cur][row * BK + sb * 8];
            }
        }

        // Stage tile kt+BK (already in regs) into the other buffer, then
        // refill regs with tile kt+2*BK. Both overlap the MFMA below; the
        // end-of-iter barrier (vmcnt+lgkm drain) is the only fence.
        if (kt + BK < KTOT) {
            WRITE(cur ^ 1);
            if (kt + 2 * BK < KTOT) LOAD(kt + 2 * BK);
        }

        __builtin_amdgcn_s_setprio(1);
#pragma unroll
        for (int kc = 0; kc < 2; ++kc)
#pragma unroll
            for (int i = 0; i < 4; ++i)
#pragma unroll
                for (int j = 0; j < 4; ++j)
                    acc[i][j] = __builtin_amdgcn_mfma_f32_16x16x32_bf16(
                        af[kc][i], bfr[kc][j], acc[i][j], 0, 0, 0);
        __builtin_amdgcn_s_setprio(0);
        __syncthreads();
    }

    // Epilogue: C/D layout col = lane&15 (n), row = quad*4 + r (m) [m89]
#pragma unroll
    for (int i = 0; i < 4; ++i)
#pragma unroll
        for (int j = 0; j < 4; ++j) {
            const int n = n0 + wc * 64 + j * 16 + lm;
#pragma unroll
            for (int r = 0; r < 4; ++r) {
                const int m = m0 + wr * 64 + i * 16 + quad * 4 + r;
                C[(size_t)m * NN + n] = acc[i][j][r];
            }
        }
}

extern "C" void kernel_launch(void* const* d_in, const int* in_sizes, int n_in,
                              void* d_out, int out_size, void* d_ws, size_t ws_size,
                              hipStream_t stream) {
    const float* A = (const float*)d_in[0];  // [8,8192,512]
    const float* B = (const float*)d_in[1];  // [8,1024,512]
    float* C = (float*)d_out;                // [8192,1024]
    (void)d_ws; (void)ws_size;

    dim3 grid(NN / BN, MM / BM);  // (8, 64) = 512 blocks
    gemm_rs_fused2<<<grid, 256, 0, stream>>>(A, B, C);
}